// Round 1
// baseline (128.977 us; speedup 1.0000x reference)
//
#include <hip/hip_runtime.h>

#define KDIM 64
#define VDIM 64
#define MDIM 2048
#define BDIM 512
#define INDIM 512
#define HDIM 192          // 2K+V
#define CIN 768           // IN + 2K + 2V
#define O_SIZE (BDIM*HDIM) // 98304

__global__ __launch_bounds__(512, 4)
void memlinear_kernel(const float* __restrict__ x,
                      const float* __restrict__ hidden,
                      const float* __restrict__ content,
                      const float* __restrict__ key_mem,
                      const float* __restrict__ value_mem,
                      const float* __restrict__ W,
                      const float* __restrict__ bias,
                      float* __restrict__ out)
{
    const int b    = blockIdx.x;
    const int tid  = threadIdx.x;
    const int lane = tid & 63;
    const int wid  = tid >> 6;

    __shared__ __align__(16) float inp[CIN];       // 768 f32 = 3 KB
    __shared__ float q[KDIM];                      // 64
    __shared__ float red[8];
    __shared__ __align__(16) float attn_lds[MDIM]; // 8 KB

    // ---- Phase A: stage concat input, tiny GEMM o = inp @ W^T + b ----
    if (tid < INDIM) inp[tid] = x[(size_t)b*INDIM + tid];
    if (tid < HDIM)  inp[INDIM + tid] = fmaxf(hidden[(size_t)b*HDIM + tid], 0.f);
    if (tid < VDIM)  inp[INDIM + HDIM + tid] = content[(size_t)b*VDIM + tid];
    __syncthreads();

    if (tid < HDIM) {
        const float4* w4 = reinterpret_cast<const float4*>(W) + (size_t)tid * (CIN/4);
        const float4* i4 = reinterpret_cast<const float4*>(inp);
        float ax = 0.f, ay = 0.f, az = 0.f, aw = 0.f;
        #pragma unroll 8
        for (int i = 0; i < CIN/4; ++i) {
            float4 w = w4[i];
            float4 v = i4[i];
            ax = fmaf(w.x, v.x, ax);
            ay = fmaf(w.y, v.y, ay);
            az = fmaf(w.z, v.z, az);
            aw = fmaf(w.w, v.w, aw);
        }
        float o = (ax + ay) + (az + aw) + bias[tid];
        out[(size_t)b*HDIM + tid] = o;
        if (tid < KDIM) q[tid] = o;
    }
    __syncthreads();

    // ---- Phase B: scores[m] = sum_k key_mem[b,k,m] * q[k], 4 m's/thread ----
    const float4* km4 = reinterpret_cast<const float4*>(key_mem + (size_t)b*KDIM*MDIM);
    float4 s = make_float4(0.f, 0.f, 0.f, 0.f);
    #pragma unroll 8
    for (int k = 0; k < KDIM; ++k) {
        float qk = q[k];
        float4 kk = km4[(size_t)k*(MDIM/4) + tid];
        s.x = fmaf(qk, kk.x, s.x);
        s.y = fmaf(qk, kk.y, s.y);
        s.z = fmaf(qk, kk.z, s.z);
        s.w = fmaf(qk, kk.w, s.w);
    }

    // ---- Phase C: softmax over m (block-wide, 8 waves) ----
    float mx = fmaxf(fmaxf(s.x, s.y), fmaxf(s.z, s.w));
    #pragma unroll
    for (int off = 32; off >= 1; off >>= 1)
        mx = fmaxf(mx, __shfl_xor(mx, off));
    if (lane == 0) red[wid] = mx;
    __syncthreads();
    float m_all = red[0];
    #pragma unroll
    for (int w = 1; w < 8; ++w) m_all = fmaxf(m_all, red[w]);

    float4 e;
    e.x = __expf(s.x - m_all);
    e.y = __expf(s.y - m_all);
    e.z = __expf(s.z - m_all);
    e.w = __expf(s.w - m_all);
    float sum = (e.x + e.y) + (e.z + e.w);
    #pragma unroll
    for (int off = 32; off >= 1; off >>= 1)
        sum += __shfl_xor(sum, off);
    __syncthreads();                 // everyone done reading red (max)
    if (lane == 0) red[wid] = sum;
    __syncthreads();
    float total = 0.f;
    #pragma unroll
    for (int w = 0; w < 8; ++w) total += red[w];
    float inv = 1.0f / total;

    reinterpret_cast<float4*>(attn_lds)[tid] =
        make_float4(e.x*inv, e.y*inv, e.z*inv, e.w*inv);
    __syncthreads();

    // ---- Phase D: content_new[v] = sum_m value_mem[b,v,m] * attn[m] ----
    // wave `wid` handles v in [wid*8, wid*8+8)
    const float4* vm4 = reinterpret_cast<const float4*>(value_mem + (size_t)b*VDIM*MDIM);
    const float4* a4  = reinterpret_cast<const float4*>(attn_lds);
    #pragma unroll
    for (int vi = 0; vi < 8; ++vi) {
        int v = wid*8 + vi;
        float px = 0.f, py = 0.f, pz = 0.f, pw = 0.f;
        #pragma unroll
        for (int i = 0; i < 8; ++i) {
            float4 vv = vm4[(size_t)v*(MDIM/4) + i*64 + lane];
            float4 aa = a4[i*64 + lane];
            px = fmaf(vv.x, aa.x, px);
            py = fmaf(vv.y, aa.y, py);
            pz = fmaf(vv.z, aa.z, pz);
            pw = fmaf(vv.w, aa.w, pw);
        }
        float p = (px + py) + (pz + pw);
        #pragma unroll
        for (int off = 32; off >= 1; off >>= 1)
            p += __shfl_xor(p, off);
        if (lane == 0) out[O_SIZE + (size_t)b*VDIM + v] = p;
    }
}

extern "C" void kernel_launch(void* const* d_in, const int* in_sizes, int n_in,
                              void* d_out, int out_size, void* d_ws, size_t ws_size,
                              hipStream_t stream) {
    const float* x         = (const float*)d_in[0];
    const float* hidden    = (const float*)d_in[1];
    const float* content   = (const float*)d_in[2];
    const float* key_mem   = (const float*)d_in[3];
    const float* value_mem = (const float*)d_in[4];
    const float* W         = (const float*)d_in[5];
    const float* bias      = (const float*)d_in[6];
    float* out = (float*)d_out;

    memlinear_kernel<<<dim3(BDIM), dim3(512), 0, stream>>>(
        x, hidden, content, key_mem, value_mem, W, bias, out);
}